// Round 8
// baseline (121.207 us; speedup 1.0000x reference)
//
#include <hip/hip_runtime.h>
#include <math.h>

// Problem constants
constexpr int N = 8, C = 128, H = 64, W = 64;
constexpr int PIX = H * W;            // 4096
constexpr int KK = 49;                // 7x7 window

// ws layout in floats
constexpr size_t M_OFF   = 0;                        // M = W1^T W2, 128x128
constexpr size_t WT3_OFF = 16384;                    // W3 transposed [k][o]
constexpr size_t Z_OFF   = 65536;                    // z = M^T x, N*C*PIX
constexpr size_t YSZ     = (size_t)N * C * PIX;      // 4,194,304 floats
constexpr size_t SIM_OFF = Z_OFF + YSZ;              // sim: [n*16+hq][49][256] fp32
constexpr size_t SIMSZ   = (size_t)N * 16 * KK * 256;// 1,605,632 floats
constexpr size_t ATTG_OFF= SIM_OFF + SIMSZ;          // attn bf16, same shape (805k floats)
constexpr size_t U_OFF   = ATTG_OFF + SIMSZ / 2 + 64;// u = PV(x), N*C*PIX

constexpr int SLW = 76;   // padded stage row width; image col v -> col 4+v
constexpr int ALR = 72;   // attn LDS r-stride (ushorts): 144 B = +4 banks

// ---------------------------------------------------------------------------
// K0: prep. Blocks 0..63: M[a][b] = sum_c W1[c][a]*W2[c][b]  (2 rows/block).
//     Blocks 64..67: Wt3[c][o] = W3[o][c].
// ---------------------------------------------------------------------------
__global__ __launch_bounds__(256) void prep(const float* __restrict__ w1,
                                            const float* __restrict__ w2,
                                            const float* __restrict__ w3,
                                            float* __restrict__ Mout,
                                            float* __restrict__ wt3) {
    int bid = blockIdx.x, tid = threadIdx.x;
    if (bid < 64) {
        int a = bid * 2 + (tid >> 7);
        int b = tid & 127;
        float s = 0.f;
        for (int c = 0; c < 128; c++)
            s = fmaf(w1[c * 128 + a], w2[c * 128 + b], s);
        Mout[a * 128 + b] = s;
    } else {
        int base = (bid - 64) * 4096;
        for (int i = tid; i < 4096; i += 256) {
            int idx = base + i;
            int o = idx & 127, c = idx >> 7;
            wt3[idx] = w3[o * 128 + c];     // wt3[c*128+o] = w3[o][c]
        }
    }
}

// ---------------------------------------------------------------------------
// K1: generic 1x1-conv GEMM. Block tile: 128 oc x 64 px, K=128 chunked by 32.
// ---------------------------------------------------------------------------
__global__ __launch_bounds__(256) void convk(const float* __restrict__ A,
                                             const float* __restrict__ Bsrc,
                                             float* __restrict__ Yout) {
    __shared__ float la[32 * 136];   // [k][oc], pad 8
    __shared__ float lb[32 * 72];    // [k][px], pad 8

    int bid = blockIdx.x;
    int pt  = bid & 63;
    int n   = bid >> 6;
    int p0  = pt * 64;

    const float* B = Bsrc + (size_t)n * C * PIX;
    float*       Y = Yout + (size_t)n * C * PIX;

    int tid = threadIdx.x;
    int tx  = tid & 15, ty = tid >> 4;
    int oc0 = ty * 8, px0 = tx * 4;

    float acc[8][4];
#pragma unroll
    for (int i = 0; i < 8; i++)
#pragma unroll
        for (int j = 0; j < 4; j++) acc[i][j] = 0.f;

    for (int kk = 0; kk < 128; kk += 32) {
#pragma unroll
        for (int i = 0; i < 4; i++) {
            int q   = tid + i * 256;
            int row = q >> 5;
            int c4  = (q & 31) * 4;
            *(float4*)&la[row * 136 + c4] =
                *(const float4*)&A[(kk + row) * 128 + c4];
        }
#pragma unroll
        for (int i = 0; i < 2; i++) {
            int q   = tid + i * 256;
            int row = q >> 4;
            int c4  = (q & 15) * 4;
            *(float4*)&lb[row * 72 + c4] =
                *(const float4*)&B[(size_t)(kk + row) * PIX + p0 + c4];
        }
        __syncthreads();

#pragma unroll 8
        for (int k = 0; k < 32; k++) {
            float4 a0 = *(float4*)&la[k * 136 + oc0];
            float4 a1 = *(float4*)&la[k * 136 + oc0 + 4];
            float4 b0 = *(float4*)&lb[k * 72 + px0];
            float a[8] = {a0.x, a0.y, a0.z, a0.w, a1.x, a1.y, a1.z, a1.w};
            float b[4] = {b0.x, b0.y, b0.z, b0.w};
#pragma unroll
            for (int i = 0; i < 8; i++)
#pragma unroll
                for (int j = 0; j < 4; j++)
                    acc[i][j] = fmaf(a[i], b[j], acc[i][j]);
        }
        __syncthreads();
    }

#pragma unroll
    for (int i = 0; i < 8; i++) {
        float4 v = make_float4(acc[i][0], acc[i][1], acc[i][2], acc[i][3]);
        *(float4*)&Y[(size_t)(oc0 + i) * PIX + p0 + px0] = v;
    }
}

// ---------------------------------------------------------------------------
// K2: sim[n][hq][k][px] for k = di*7+dj.  ONE di PER BLOCK (4 staged rows).
// Grid 896: bid = di*128 + g, g = n*16+hq.
// LDS stage layout: st[(c*4 + row)*SLW + col]  (r-stride 76 ≡ 12 banks).
// ---------------------------------------------------------------------------
__global__ __launch_bounds__(256) void simk2(const float* __restrict__ z,
                                             const float* __restrict__ x,
                                             float* __restrict__ sim) {
    __shared__ __align__(16) float st[5376];  // stage 16*4*76=4864 | red 3*7*256=5376

    int bid = blockIdx.x;
    int di  = bid >> 7;          // 0..6
    int g   = bid & 127;
    int n   = g >> 4;
    int hq  = g & 15;
    int h0  = hq * 4;

    int tid  = threadIdx.x;
    int wid  = tid >> 6;
    int lane = tid & 63;
    int r = lane >> 4, w4 = lane & 15, wpx = w4 * 4;

    const float* zb = z + (size_t)n * C * PIX;
    const float* xb = x + (size_t)n * C * PIX;
    float* simb = sim + ((size_t)g * KK) * 256;

    // zero halo columns (16 c x 4 rows x 8 halo cols)
    for (int idx = tid; idx < 16 * 4 * 8; idx += 256) {
        int col8 = idx & 7;
        int row  = (idx >> 3) & 3;
        int c    = idx >> 5;
        int col  = (col8 < 4) ? col8 : 64 + col8;
        st[(c * 4 + row) * SLW + col] = 0.f;
    }
    __syncthreads();

    float acc[7][4];
#pragma unroll
    for (int dj = 0; dj < 7; dj++)
#pragma unroll
        for (int j = 0; j < 4; j++) acc[dj][j] = 0.f;

    for (int ch = 0; ch < C; ch += 16) {
#pragma unroll
        for (int i = 0; i < 4; i++) {
            int q  = tid + i * 256;
            int qw = q & 15, qc = (q >> 4) & 15, qr = q >> 8;
            int hh = h0 + di - 3 + qr;
            float4 v = make_float4(0.f, 0.f, 0.f, 0.f);
            if ((unsigned)hh < 64u)
                v = *(const float4*)&xb[(size_t)(ch + qc) * PIX + hh * 64 + qw * 4];
            *(float4*)&st[(qc * 4 + qr) * SLW + 4 + qw * 4] = v;
        }
        __syncthreads();

#pragma unroll
        for (int c = 0; c < 4; c++) {
            int cl = wid * 4 + c;
            float4 z4 = *(const float4*)&zb[(size_t)(ch + cl) * PIX + (h0 + r) * 64 + wpx];
            const float* rp = &st[(cl * 4 + r) * SLW + wpx];
            float rw[12];
            *(float4*)&rw[0] = *(const float4*)&rp[0];
            *(float4*)&rw[4] = *(const float4*)&rp[4];
            *(float4*)&rw[8] = *(const float4*)&rp[8];
            const float* zp = (const float*)&z4;
#pragma unroll
            for (int dj = 0; dj < 7; dj++)
#pragma unroll
                for (int j = 0; j < 4; j++)
                    acc[dj][j] = fmaf(zp[j], rw[j + dj + 1], acc[dj][j]);
        }
        __syncthreads();
    }

    // cross-wave channel reduction (stage buffer dead)
    if (wid > 0) {
#pragma unroll
        for (int dj = 0; dj < 7; dj++) {
            float4 v = make_float4(acc[dj][0], acc[dj][1], acc[dj][2], acc[dj][3]);
            *(float4*)&st[((wid - 1) * 7 + dj) * 256 + lane * 4] = v;
        }
    }
    __syncthreads();
    if (wid == 0) {
#pragma unroll
        for (int s = 0; s < 3; s++)
#pragma unroll
            for (int dj = 0; dj < 7; dj++) {
                float4 v = *(const float4*)&st[(s * 7 + dj) * 256 + lane * 4];
                acc[dj][0] += v.x; acc[dj][1] += v.y;
                acc[dj][2] += v.z; acc[dj][3] += v.w;
            }
#pragma unroll
        for (int dj = 0; dj < 7; dj++) {
            int k = di * 7 + dj;
            float4 v = make_float4(acc[dj][0], acc[dj][1], acc[dj][2], acc[dj][3]);
            *(float4*)&simb[(size_t)k * 256 + r * 64 + wpx] = v;
        }
    }
}

// ---------------------------------------------------------------------------
// K2.5: softmax over 49 per pixel, ONCE per (n,hq).  Grid 128, 256 thr.
// sim fp32 [g][49][256] -> attn bf16 [g][49][256].
// ---------------------------------------------------------------------------
__global__ __launch_bounds__(256) void softk(const float* __restrict__ sim,
                                             unsigned short* __restrict__ attn_g) {
    int g  = blockIdx.x;
    int px = threadIdx.x;
    const float* simb = sim + ((size_t)g * KK) * 256;
    unsigned short* ab = attn_g + ((size_t)g * KK) * 256;

    float sv[KK];
    float m = -1e30f;
#pragma unroll
    for (int k = 0; k < KK; k++) {
        sv[k] = simb[(size_t)k * 256 + px];
        m = fmaxf(m, sv[k]);
    }
    float s = 0.f;
#pragma unroll
    for (int k = 0; k < KK; k++) {
        float e = __expf(sv[k] - m);
        sv[k] = e; s += e;
    }
    float inv = 1.f / s;
#pragma unroll
    for (int k = 0; k < KK; k++) {
        unsigned ui = __float_as_uint(sv[k] * inv);
        ui += 0x7FFFu + ((ui >> 16) & 1u);   // RNE to bf16
        ab[k * 256 + px] = (unsigned short)(ui >> 16);
    }
}

// ---------------------------------------------------------------------------
// K3: u[c](p) = sum_k attn_k(p) x_c(p+dk).  Grid 512: bid = cqb*128 + g.
// Stage layout: st[(c*10 + row)*SLW + col] (r-stride 76 ≡ 12 banks).
// attn LDS layout: al[k*4*ALR + r*ALR + w] (r-stride 72 ush = 144 B ≡ 4 banks)
// -> both LDS read streams conflict-free.
// ---------------------------------------------------------------------------
__global__ __launch_bounds__(512) void softpv3(const unsigned short* __restrict__ attn_g,
                                               const float* __restrict__ x,
                                               float* __restrict__ u) {
    __shared__ __align__(16) float st[16 * 10 * SLW];       // 48.6 KB
    __shared__ __align__(16) unsigned short al[KK * 4 * ALR]; // 28.2 KB

    int bid = blockIdx.x;
    int cqb = bid >> 7;          // 0..3 c-quarter
    int g   = bid & 127;
    int n   = g >> 4;
    int hq  = g & 15;
    int h0  = hq * 4;

    int tid  = threadIdx.x;
    int wid  = tid >> 6;
    int lane = tid & 63;
    int r = lane >> 4, w4 = lane & 15, wpx = w4 * 4;

    const float* xb = x + (size_t)n * C * PIX;
    const unsigned short* ag = attn_g + ((size_t)g * KK) * 256;
    float* ub = u + (size_t)n * C * PIX;

    // copy attn into padded LDS layout (coalesced global reads)
    for (int idx = tid; idx < KK * 256; idx += 512) {
        int k = idx >> 8, px = idx & 255;
        al[k * (4 * ALR) + (px >> 6) * ALR + (px & 63)] = ag[idx];
    }
    // zero halo columns (16 c x 10 rows x 8 cols)
    for (int idx = tid; idx < 16 * 10 * 8; idx += 512) {
        int col8 = idx & 7;
        int row  = (idx >> 3) % 10;
        int c    = (idx >> 3) / 10;
        int col  = (col8 < 4) ? col8 : 64 + col8;
        st[(c * 10 + row) * SLW + col] = 0.f;
    }
    __syncthreads();

    for (int ch2 = 0; ch2 < 2; ch2++) {
        int c0 = cqb * 32 + ch2 * 16;
        // stage 16 c x 10 rows (c-major layout)
#pragma unroll
        for (int i = 0; i < 5; i++) {
            int q  = tid + i * 512;
            int qw = q & 15, qc = (q >> 4) & 15, qr = q >> 8;
            int hh = h0 - 3 + qr;
            float4 v = make_float4(0.f, 0.f, 0.f, 0.f);
            if ((unsigned)hh < 64u)
                v = *(const float4*)&xb[(size_t)(c0 + qc) * PIX + hh * 64 + qw * 4];
            *(float4*)&st[(qc * 10 + qr) * SLW + 4 + qw * 4] = v;
        }
        __syncthreads();

        int cw = wid * 2;
        float u4[2][4];
#pragma unroll
        for (int cl = 0; cl < 2; cl++)
#pragma unroll
            for (int j = 0; j < 4; j++) u4[cl][j] = 0.f;

        for (int di = 0; di < 7; di++) {
            float a[7][4];
#pragma unroll
            for (int dj = 0; dj < 7; dj++) {
                uint2 p = *(const uint2*)&al[(di * 7 + dj) * (4 * ALR) + r * ALR + wpx];
                a[dj][0] = __uint_as_float((p.x & 0xFFFFu) << 16);
                a[dj][1] = __uint_as_float(p.x & 0xFFFF0000u);
                a[dj][2] = __uint_as_float((p.y & 0xFFFFu) << 16);
                a[dj][3] = __uint_as_float(p.y & 0xFFFF0000u);
            }
#pragma unroll
            for (int cl = 0; cl < 2; cl++) {
                const float* rp = &st[((cw + cl) * 10 + r + di) * SLW + wpx];
                float rw[12];
                *(float4*)&rw[0] = *(const float4*)&rp[0];
                *(float4*)&rw[4] = *(const float4*)&rp[4];
                *(float4*)&rw[8] = *(const float4*)&rp[8];
#pragma unroll
                for (int dj = 0; dj < 7; dj++)
#pragma unroll
                    for (int j = 0; j < 4; j++)
                        u4[cl][j] = fmaf(a[dj][j], rw[j + dj + 1], u4[cl][j]);
            }
        }

#pragma unroll
        for (int cl = 0; cl < 2; cl++) {
            int c = c0 + cw + cl;
            float4 v = make_float4(u4[cl][0], u4[cl][1], u4[cl][2], u4[cl][3]);
            *(float4*)&ub[(size_t)c * PIX + (h0 + r) * 64 + wpx] = v;
        }
        __syncthreads();
    }
}

// ---------------------------------------------------------------------------
extern "C" void kernel_launch(void* const* d_in, const int* in_sizes, int n_in,
                              void* d_out, int out_size, void* d_ws, size_t ws_size,
                              hipStream_t stream) {
    const float* x  = (const float*)d_in[0];
    const float* w1 = (const float*)d_in[1];
    const float* w2 = (const float*)d_in[2];
    const float* w3 = (const float*)d_in[3];
    float* wsf = (float*)d_ws;
    unsigned short* attn_g = (unsigned short*)(wsf + ATTG_OFF);

    prep<<<68, 256, 0, stream>>>(w1, w2, w3, wsf + M_OFF, wsf + WT3_OFF);
    convk<<<512, 256, 0, stream>>>(wsf + M_OFF, x, wsf + Z_OFF);               // z = M^T x
    simk2<<<896, 256, 0, stream>>>(wsf + Z_OFF, x, wsf + SIM_OFF);             // sim
    softk<<<128, 256, 0, stream>>>(wsf + SIM_OFF, attn_g);                     // softmax
    softpv3<<<512, 512, 0, stream>>>(attn_g, x, wsf + U_OFF);                  // u = PV(x)
    convk<<<512, 256, 0, stream>>>(wsf + WT3_OFF, wsf + U_OFF, (float*)d_out); // out = W3 u
}